// Round 6
// baseline (187.425 us; speedup 1.0000x reference)
//
#include <hip/hip_runtime.h>
#include <math.h>

#define NBLK 1024
#define SCALE 0.17677669529663687f

typedef short short8 __attribute__((ext_vector_type(8)));
typedef float f32x4 __attribute__((ext_vector_type(4)));
typedef unsigned int u32x4 __attribute__((ext_vector_type(4)));
typedef unsigned short ushort_t;

__device__ __forceinline__ unsigned short f2bf(float x) {
  unsigned int u = __float_as_uint(x);
  u += 0x7fffu + ((u >> 16) & 1u);
  return (unsigned short)(u >> 16);
}
__device__ __forceinline__ unsigned pk2(float a, float b) {
  return (unsigned)f2bf(a) | ((unsigned)f2bf(b) << 16);
}
__device__ __forceinline__ short8 asfrag(u32x4 v) {
  return __builtin_bit_cast(short8, v);
}
// [16 rows][32 k] bf16 tile, XOR-swizzled (used by prep only)
__device__ __forceinline__ int tile_addr(int r, int k) {
  int g = k >> 3;
  int p = (g ^ ((r >> 1) & 3)) & 3;
  return r * 32 + p * 8 + (k & 7);
}

// kg-regroup: source lanes hold D[h=nt*16+kg*4+reg][col=r] packed as p01/p23 per nt.
// Returns B/A-frag dwords for h-chunk c: elem j at lane(kg,r) = X[h=c*32+kg*8+j][col=r].
__device__ __forceinline__ u32x4 regroup4(unsigned p01e, unsigned p23e, unsigned p01o,
                                          unsigned p23o, int s0, int s1, bool hi) {
  u32x4 o;
  int a0 = __shfl((int)p01e, s0), b0 = __shfl((int)p01o, s0);
  int a1 = __shfl((int)p23e, s0), b1 = __shfl((int)p23o, s0);
  int a2 = __shfl((int)p01e, s1), b2 = __shfl((int)p01o, s1);
  int a3 = __shfl((int)p23e, s1), b3 = __shfl((int)p23o, s1);
  o.x = (unsigned)(hi ? b0 : a0);
  o.y = (unsigned)(hi ? b1 : a1);
  o.z = (unsigned)(hi ? b2 : a2);
  o.w = (unsigned)(hi ? b3 : a3);
  return o;
}

// ---- prep: unchanged (verified rounds 4-5) ----
// wbf (shorts): W1 [0,16384): ((gi*16 + nt*2+kc)*64+lane)*8
//   Wkv [16384,53248): ((gi*36 + nt*4+kc)*64+lane)*8   (nt=8 tile = vw2 rows 0..3, rows 4..15 zero)
//   Wq  [53248,86016): ((gi*32 + nt*4+kc)*64+lane)*8
// wsf (floats at byte 172032): per gi stride 1024: [512..515] vb2, [516] const
__global__ void prep(const float* __restrict__ fc1_w, const float* __restrict__ qkv_w,
                     const float* __restrict__ qkv_b, const float* __restrict__ out_w,
                     const float* __restrict__ out_b, const float* __restrict__ fc2_w,
                     const float* __restrict__ fc2_b,
                     unsigned short* __restrict__ wbf, float* __restrict__ wsf) {
  const int blk = blockIdx.x;
  const int t = threadIdx.x;
  __shared__ float cw[128], red[256], ow2s[32];
  if (blk < 40) {
    int o = blk * 256 + t;
    const float* src;
    int dst;
    if (o < 2048) {  // W1: 2gi x 128n x 8kg
      int gi = o >> 10, rem = o & 1023, n = rem >> 3, kg = rem & 7;
      int g = gi ? 3 : 1;
      src = fc1_w + ((g << 7) + n) * 64 + kg * 8;
      int lane = (kg & 3) * 16 + (n & 15);
      int f = (n >> 4) * 2 + (kg >> 2);
      dst = ((gi * 16 + f) * 64 + lane) * 8;
    } else if (o < 6144) {  // Wk -> Wkv nt<8
      int o2 = o - 2048;
      int gi = o2 >> 11, rem = o2 & 2047, n = rem >> 4, kg = rem & 15;
      int g = gi ? 3 : 1;
      src = qkv_w + ((g * 384 + 128 + n) << 7) + kg * 8;
      int lane = (kg & 3) * 16 + (n & 15);
      int f = (n >> 4) * 4 + (kg >> 2);
      dst = 16384 + ((gi * 36 + f) * 64 + lane) * 8;
    } else {  // Wq
      int o2 = o - 6144;
      int gi = o2 >> 11, rem = o2 & 2047, n = rem >> 4, kg = rem & 15;
      int g = gi ? 3 : 1;
      src = qkv_w + ((g * 384 + n) << 7) + kg * 8;
      int lane = (kg & 3) * 16 + (n & 15);
      int f = (n >> 4) * 4 + (kg >> 2);
      dst = 53248 + ((gi * 32 + f) * 64 + lane) * 8;
    }
    float4 v0 = *(const float4*)src;
    float4 v1 = *(const float4*)(src + 4);
    uint4 p;
    p.x = pk2(v0.x, v0.y); p.y = pk2(v0.z, v0.w);
    p.z = pk2(v1.x, v1.y); p.w = pk2(v1.z, v1.w);
    *(uint4*)&wbf[dst] = p;
  } else {
    const int mb = blk - 40;       // 8 blocks: gi x hh
    const int gi = mb >> 2, hh = mb & 3;
    const int g = gi ? 3 : 1;
    {
      const float* fw = fc2_w + g * 4096;
      int h2 = t & 127, half = t >> 7;
      float s = 0.f;
      for (int e = half * 16; e < half * 16 + 16; ++e) s += fw[e * 128 + h2];
      red[t] = s;
    }
    __syncthreads();
    if (t < 128) cw[t] = red[t] + red[t + 128];
    __syncthreads();
    {
      const float* ow = out_w + g * 16384;
      int hp = hh * 32 + (t & 31), ch = t >> 5;
      float s = 0.f;
      for (int h = ch * 16; h < ch * 16 + 16; ++h) s += ow[h * 128 + hp] * cw[h];
      red[t] = s;
    }
    __syncthreads();
    if (t < 32) {
      float s = 0.f;
      for (int c = 0; c < 8; ++c) s += red[c * 32 + t];
      ow2s[t] = s;
    }
    __syncthreads();
    {
      const float* qwv = qkv_w + (size_t)(g * 3 + 2) * 16384;
      int h2 = t & 127, half = t >> 7;
      float s = 0.f;
      for (int d = half * 16; d < half * 16 + 16; ++d)
        s += qwv[(hh * 32 + d) * 128 + h2] * ow2s[d];
      red[t] = s;
    }
    __syncthreads();
    if (t < 128) {
      float v = red[t] + red[t + 128];
      int k = t, kc = k >> 5, kg2 = k >> 3, j = k & 7;
      wbf[16384 + ((gi * 36 + 32 + kc) * 64 + ((kg2 & 3) * 16 + hh)) * 8 + j] = f2bf(v);
    }
    if (t < 32) red[t] = qkv_b[g * 384 + 256 + hh * 32 + t] * ow2s[t];
    __syncthreads();
    if (t < 32) {
      float s = red[t];
      for (int o = 16; o; o >>= 1) s += __shfl_xor(s, o, 32);
      if (t == 0) wsf[gi * 1024 + 512 + hh] = s;
    }
    if (hh == 0) {
      for (int idx = t; idx < 1536; idx += 256) {
        int n = 4 + (idx >> 7), k = idx & 127;
        int kc = k >> 5, kg2 = k >> 3, j = k & 7;
        wbf[16384 + ((gi * 36 + 32 + kc) * 64 + ((kg2 & 3) * 16 + n)) * 8 + j] = 0;
      }
      if (t < 128) red[t] = out_b[g * 128 + t] * cw[t] + (t < 32 ? fc2_b[g * 32 + t] : 0.f);
      __syncthreads();
      if (t < 64) {
        float s = red[t] + red[t + 64];
        for (int o = 32; o; o >>= 1) s += __shfl_xor(s, o, 64);
        if (t == 0) wsf[gi * 1024 + 516] = s;
      }
    }
  }
}

// ---- mixer: one wave = one batch element, zero LDS, zero barriers ----
__global__ __launch_bounds__(256, 2)
void mixer(const float* __restrict__ agent_qs,
           const float* __restrict__ entities,
           const int* __restrict__ emask,
           const float* __restrict__ fc1_b,
           const float* __restrict__ qkv_b,
           const unsigned short* __restrict__ wbf,
           const float* __restrict__ wsf,
           float* __restrict__ out) {
  const int t = threadIdx.x;
  const int lane = t & 63;
  const int kg = lane >> 4, r = lane & 15;
  const int b = blockIdx.x * 4 + (t >> 6);

  const short8* W1f = (const short8*)wbf;
  const short8* Wkvf = (const short8*)(wbf + 16384);
  const short8* Wqf = (const short8*)(wbf + 53248);

  // masks (one int per lane, distributed via shfl)
  const int mlane = emask[b * 32 + (lane & 31)];
  const bool me0 = __shfl(mlane, r) == 0;       // entity r attended?
  const bool me1 = __shfl(mlane, 16 + r) == 0;  // entity 16+r
  bool aa[4];
#pragma unroll
  for (int reg = 0; reg < 4; ++reg) aa[reg] = __shfl(mlane, (kg * 4 + reg) & 7) == 0;
  const int cnt = __popcll(__ballot((lane < 8) && (mlane == 0)));

  // E fragments straight from global: B[k=ed][col=ent]
  u32x4 ef[2][2];
#pragma unroll
  for (int mt = 0; mt < 2; ++mt)
#pragma unroll
    for (int kc = 0; kc < 2; ++kc) {
      const float4* ep =
          (const float4*)(entities + (size_t)b * 2048 + (mt * 16 + r) * 64 + kc * 32 + kg * 8);
      float4 u0 = ep[0], u1 = ep[1];
      u32x4 v;
      v.x = pk2(u0.x, u0.y); v.y = pk2(u0.z, u0.w);
      v.z = pk2(u1.x, u1.y); v.w = pk2(u1.z, u1.w);
      ef[mt][kc] = v;
    }

  const int s0 = ((kg & 1) << 5) + r;  // shfl sources for kg-regroup
  const int s1 = s0 + 16;
  const bool hi = (kg >> 1) != 0;

  float T = 0.f;
  for (int gi = 0; gi < 2; ++gi) {
    const int g = gi ? 3 : 1;
    // ---- x1 = relu(E @ W1^T + b1): D[h][ent] ----
    f32x4 ax[8][2];
#pragma unroll
    for (int nt = 0; nt < 8; ++nt)
#pragma unroll
      for (int mt = 0; mt < 2; ++mt) ax[nt][mt] = {0.f, 0.f, 0.f, 0.f};
#pragma unroll
    for (int kc = 0; kc < 2; ++kc)
#pragma unroll
      for (int nt = 0; nt < 8; ++nt) {
        short8 wf = W1f[(gi * 16 + nt * 2 + kc) * 64 + lane];
#pragma unroll
        for (int mt = 0; mt < 2; ++mt)
          ax[nt][mt] = __builtin_amdgcn_mfma_f32_16x16x32_bf16(wf, asfrag(ef[mt][kc]), ax[nt][mt], 0, 0, 0);
      }
    unsigned p01x[8][2], p23x[8][2];
#pragma unroll
    for (int nt = 0; nt < 8; ++nt) {
      float4 b4 = *(const float4*)&fc1_b[g * 128 + nt * 16 + kg * 4];
#pragma unroll
      for (int mt = 0; mt < 2; ++mt) {
        float v0 = fmaxf(ax[nt][mt][0] + b4.x, 0.f);
        float v1 = fmaxf(ax[nt][mt][1] + b4.y, 0.f);
        float v2 = fmaxf(ax[nt][mt][2] + b4.z, 0.f);
        float v3 = fmaxf(ax[nt][mt][3] + b4.w, 0.f);
        p01x[nt][mt] = pk2(v0, v1);
        p23x[nt][mt] = pk2(v2, v3);
      }
    }
    // regroup x1 into B-frags
    u32x4 xf[2][4];
#pragma unroll
    for (int mt = 0; mt < 2; ++mt)
#pragma unroll
      for (int c = 0; c < 4; ++c)
        xf[mt][c] = regroup4(p01x[2 * c][mt], p23x[2 * c][mt], p01x[2 * c + 1][mt],
                             p23x[2 * c + 1][mt], s0, s1, hi);
    // ---- [K | vproj] = Wkv @ x1^T: D[h][ent] (nt=8 rows 0..3 = vproj heads) ----
    f32x4 ak[9][2];
#pragma unroll
    for (int nt = 0; nt < 9; ++nt)
#pragma unroll
      for (int mt = 0; mt < 2; ++mt) ak[nt][mt] = {0.f, 0.f, 0.f, 0.f};
#pragma unroll
    for (int kc = 0; kc < 4; ++kc)
#pragma unroll
      for (int nt = 0; nt < 9; ++nt) {
        short8 wf = Wkvf[(gi * 36 + nt * 4 + kc) * 64 + lane];
#pragma unroll
        for (int mt = 0; mt < 2; ++mt)
          ak[nt][mt] = __builtin_amdgcn_mfma_f32_16x16x32_bf16(wf, asfrag(xf[mt][kc]), ak[nt][mt], 0, 0, 0);
      }
    unsigned p01k[8][2], p23k[8][2];
#pragma unroll
    for (int nt = 0; nt < 8; ++nt) {
      float4 b4 = *(const float4*)&qkv_b[g * 384 + 128 + nt * 16 + kg * 4];
#pragma unroll
      for (int mt = 0; mt < 2; ++mt) {
        p01k[nt][mt] = pk2(ak[nt][mt][0] + b4.x, ak[nt][mt][1] + b4.y);
        p23k[nt][mt] = pk2(ak[nt][mt][2] + b4.z, ak[nt][mt][3] + b4.w);
      }
    }
    // ---- Q = Wq @ x1_mt0^T: D[h][agent-col] (cols 8..15 unused) ----
    f32x4 aq[8];
#pragma unroll
    for (int nt = 0; nt < 8; ++nt) aq[nt] = {0.f, 0.f, 0.f, 0.f};
#pragma unroll
    for (int kc = 0; kc < 4; ++kc)
#pragma unroll
      for (int nt = 0; nt < 8; ++nt)
        aq[nt] = __builtin_amdgcn_mfma_f32_16x16x32_bf16(
            Wqf[(gi * 32 + nt * 4 + kc) * 64 + lane], asfrag(xf[0][kc]), aq[nt], 0, 0, 0);
    unsigned p01q[8], p23q[8];
#pragma unroll
    for (int nt = 0; nt < 8; ++nt) {
      float4 b4 = *(const float4*)&qkv_b[g * 384 + nt * 16 + kg * 4];
      p01q[nt] = pk2(aq[nt][0] + b4.x, aq[nt][1] + b4.y);
      p23q[nt] = pk2(aq[nt][2] + b4.z, aq[nt][3] + b4.w);
    }
    // ---- logits per head (h-chunk hh) + softmax + weighted vproj ----
    float c_acc = 0.f;
#pragma unroll
    for (int hh = 0; hh < 4; ++hh) {
      short8 qa = asfrag(regroup4(p01q[2 * hh], p23q[2 * hh], p01q[2 * hh + 1], p23q[2 * hh + 1],
                                  s0, s1, hi));
      short8 kb0 = asfrag(regroup4(p01k[2 * hh][0], p23k[2 * hh][0], p01k[2 * hh + 1][0],
                                   p23k[2 * hh + 1][0], s0, s1, hi));
      short8 kb1 = asfrag(regroup4(p01k[2 * hh][1], p23k[2 * hh][1], p01k[2 * hh + 1][1],
                                   p23k[2 * hh + 1][1], s0, s1, hi));
      f32x4 z = {0.f, 0.f, 0.f, 0.f};
      f32x4 d0 = __builtin_amdgcn_mfma_f32_16x16x32_bf16(qa, kb0, z, 0, 0, 0);
      f32x4 d1 = __builtin_amdgcn_mfma_f32_16x16x32_bf16(qa, kb1, z, 0, 0, 0);
      float w0[4], w1[4];
#pragma unroll
      for (int reg = 0; reg < 4; ++reg) {
        float lg0 = (me0 && aa[reg]) ? d0[reg] * SCALE : -1e30f;
        float lg1 = (me1 && aa[reg]) ? d1[reg] * SCALE : -1e30f;
        float m = fmaxf(lg0, lg1);
#pragma unroll
        for (int o = 8; o; o >>= 1) m = fmaxf(m, __shfl_xor(m, o, 16));
        float p0 = lg0 > -1e29f ? __expf(lg0 - m) : 0.f;
        float p1 = lg1 > -1e29f ? __expf(lg1 - m) : 0.f;
        float s = p0 + p1;
#pragma unroll
        for (int o = 8; o; o >>= 1) s += __shfl_xor(s, o, 16);
        float inv = s > 0.f ? 1.f / s : 0.f;
        w0[reg] = p0 * inv;
        w1[reg] = p1 * inv;
      }
      float vb2 = wsf[gi * 1024 + 512 + hh];
      float vp0 = __shfl(ak[8][0][hh], r) + vb2;
      float vp1 = __shfl(ak[8][1][hh], r) + vb2;
      float s0w = w0[0] + w0[1] + w0[2] + w0[3];
      float s1w = w1[0] + w1[1] + w1[2] + w1[3];
      c_acc = fmaf(vp0, s0w, fmaf(vp1, s1w, c_acc));
    }
#pragma unroll
    for (int o = 16; o; o >>= 1) c_acc += __shfl_xor(c_acc, o, 32);
    if (lane == 0)
      T += (c_acc + wsf[gi * 1024 + 516] * (float)cnt) * (gi ? (1.f / 256.f) : 0.125f);
  }

  if (lane == 0) {
    const float4* qs = (const float4*)(agent_qs + (size_t)b * 8);
    float4 a = qs[0], b4 = qs[1];
    out[b] = a.x + a.y + a.z + a.w + b4.x + b4.y + b4.z + b4.w + T;
  }
}

extern "C" void kernel_launch(void* const* d_in, const int* in_sizes, int n_in,
                              void* d_out, int out_size, void* d_ws, size_t ws_size,
                              hipStream_t stream) {
  const float* agent_qs = (const float*)d_in[0];
  const float* entities = (const float*)d_in[1];
  const int* emask = (const int*)d_in[2];
  const float* fc1_w = (const float*)d_in[3];
  const float* fc1_b = (const float*)d_in[4];
  const float* qkv_w = (const float*)d_in[5];
  const float* qkv_b = (const float*)d_in[6];
  const float* out_w = (const float*)d_in[7];
  const float* out_b = (const float*)d_in[8];
  const float* fc2_w = (const float*)d_in[9];
  const float* fc2_b = (const float*)d_in[10];
  float* out = (float*)d_out;
  unsigned short* wbf = (unsigned short*)d_ws;
  float* wsf = (float*)((char*)d_ws + 172032);

  prep<<<48, 256, 0, stream>>>(fc1_w, qkv_w, qkv_b, out_w, out_b, fc2_w, fc2_b, wbf, wsf);
  mixer<<<NBLK, 256, 0, stream>>>(agent_qs, entities, emask, fc1_b, qkv_b, wbf, wsf, out);
}

// Round 9
// 149.580 us; speedup vs baseline: 1.2530x; 1.2530x over previous
//
#include <hip/hip_runtime.h>
#include <math.h>

#define NBLK 4096
#define SCALE 0.17677669529663687f

typedef short short8 __attribute__((ext_vector_type(8)));
typedef float f32x4 __attribute__((ext_vector_type(4)));
typedef unsigned int u32x4 __attribute__((ext_vector_type(4)));
typedef unsigned short ushort_t;

__device__ __forceinline__ unsigned short f2bf(float x) {
  unsigned int u = __float_as_uint(x);
  u += 0x7fffu + ((u >> 16) & 1u);
  return (unsigned short)(u >> 16);
}
__device__ __forceinline__ unsigned pk2(float a, float b) {
  return (unsigned)f2bf(a) | ((unsigned)f2bf(b) << 16);
}
__device__ __forceinline__ short8 asfrag(u32x4 v) {
  return __builtin_bit_cast(short8, v);
}
// [16 rows][32 k] bf16 tile (1KB), XOR-swizzled 16B granules
__device__ __forceinline__ int tile_addr(int r, int k) {
  int g = k >> 3;
  int p = (g ^ ((r >> 1) & 3)) & 3;
  return r * 32 + p * 8 + (k & 7);
}
// row-major [rows][128] bf16, rotate-XOR swizzle
__device__ __forceinline__ int rm_addr(int r, int k) {
  int g = k >> 3;
  int r3 = r & 7;
  int rot = ((r3 << 2) | (r3 >> 1)) & 7;
  int p = (g & 8) | ((g & 7) ^ rot);
  return r * 128 + p * 8 + (k & 7);
}

// ---- prep: unchanged (verified rounds 4-6) ----
// wbf (shorts): W1 [0,16384): ((gi*16 + nt*2+kc)*64+lane)*8
//   Wkv [16384,53248): ((gi*36 + nt*4+kc)*64+lane)*8   (nt=8 tile = vw2 rows 0..3, rows 4..15 zero)
//   Wq  [53248,86016): ((gi*32 + nt*4+kc)*64+lane)*8
// wsf (floats at byte 172032): per gi stride 1024: [512..515] vb2, [516] const
__global__ void prep(const float* __restrict__ fc1_w, const float* __restrict__ qkv_w,
                     const float* __restrict__ qkv_b, const float* __restrict__ out_w,
                     const float* __restrict__ out_b, const float* __restrict__ fc2_w,
                     const float* __restrict__ fc2_b,
                     unsigned short* __restrict__ wbf, float* __restrict__ wsf) {
  const int blk = blockIdx.x;
  const int t = threadIdx.x;
  __shared__ float cw[128], red[256], ow2s[32];
  if (blk < 40) {
    int o = blk * 256 + t;
    const float* src;
    int dst;
    if (o < 2048) {  // W1: 2gi x 128n x 8kg
      int gi = o >> 10, rem = o & 1023, n = rem >> 3, kg = rem & 7;
      int g = gi ? 3 : 1;
      src = fc1_w + ((g << 7) + n) * 64 + kg * 8;
      int lane = (kg & 3) * 16 + (n & 15);
      int f = (n >> 4) * 2 + (kg >> 2);
      dst = ((gi * 16 + f) * 64 + lane) * 8;
    } else if (o < 6144) {  // Wk -> Wkv nt<8
      int o2 = o - 2048;
      int gi = o2 >> 11, rem = o2 & 2047, n = rem >> 4, kg = rem & 15;
      int g = gi ? 3 : 1;
      src = qkv_w + ((g * 384 + 128 + n) << 7) + kg * 8;
      int lane = (kg & 3) * 16 + (n & 15);
      int f = (n >> 4) * 4 + (kg >> 2);
      dst = 16384 + ((gi * 36 + f) * 64 + lane) * 8;
    } else {  // Wq
      int o2 = o - 6144;
      int gi = o2 >> 11, rem = o2 & 2047, n = rem >> 4, kg = rem & 15;
      int g = gi ? 3 : 1;
      src = qkv_w + ((g * 384 + n) << 7) + kg * 8;
      int lane = (kg & 3) * 16 + (n & 15);
      int f = (n >> 4) * 4 + (kg >> 2);
      dst = 53248 + ((gi * 32 + f) * 64 + lane) * 8;
    }
    float4 v0 = *(const float4*)src;
    float4 v1 = *(const float4*)(src + 4);
    uint4 p;
    p.x = pk2(v0.x, v0.y); p.y = pk2(v0.z, v0.w);
    p.z = pk2(v1.x, v1.y); p.w = pk2(v1.z, v1.w);
    *(uint4*)&wbf[dst] = p;
  } else {
    const int mb = blk - 40;       // 8 blocks: gi x hh
    const int gi = mb >> 2, hh = mb & 3;
    const int g = gi ? 3 : 1;
    {
      const float* fw = fc2_w + g * 4096;
      int h2 = t & 127, half = t >> 7;
      float s = 0.f;
      for (int e = half * 16; e < half * 16 + 16; ++e) s += fw[e * 128 + h2];
      red[t] = s;
    }
    __syncthreads();
    if (t < 128) cw[t] = red[t] + red[t + 128];
    __syncthreads();
    {
      const float* ow = out_w + g * 16384;
      int hp = hh * 32 + (t & 31), ch = t >> 5;
      float s = 0.f;
      for (int h = ch * 16; h < ch * 16 + 16; ++h) s += ow[h * 128 + hp] * cw[h];
      red[t] = s;
    }
    __syncthreads();
    if (t < 32) {
      float s = 0.f;
      for (int c = 0; c < 8; ++c) s += red[c * 32 + t];
      ow2s[t] = s;
    }
    __syncthreads();
    {
      const float* qwv = qkv_w + (size_t)(g * 3 + 2) * 16384;
      int h2 = t & 127, half = t >> 7;
      float s = 0.f;
      for (int d = half * 16; d < half * 16 + 16; ++d)
        s += qwv[(hh * 32 + d) * 128 + h2] * ow2s[d];
      red[t] = s;
    }
    __syncthreads();
    if (t < 128) {
      float v = red[t] + red[t + 128];
      int k = t, kc = k >> 5, kg2 = k >> 3, j = k & 7;
      wbf[16384 + ((gi * 36 + 32 + kc) * 64 + ((kg2 & 3) * 16 + hh)) * 8 + j] = f2bf(v);
    }
    if (t < 32) red[t] = qkv_b[g * 384 + 256 + hh * 32 + t] * ow2s[t];
    __syncthreads();
    if (t < 32) {
      float s = red[t];
      for (int o = 16; o; o >>= 1) s += __shfl_xor(s, o, 32);
      if (t == 0) wsf[gi * 1024 + 512 + hh] = s;
    }
    if (hh == 0) {
      for (int idx = t; idx < 1536; idx += 256) {
        int n = 4 + (idx >> 7), k = idx & 127;
        int kc = k >> 5, kg2 = k >> 3, j = k & 7;
        wbf[16384 + ((gi * 36 + 32 + kc) * 64 + ((kg2 & 3) * 16 + n)) * 8 + j] = 0;
      }
      if (t < 128) red[t] = out_b[g * 128 + t] * cw[t] + (t < 32 ? fc2_b[g * 32 + t] : 0.f);
      __syncthreads();
      if (t < 64) {
        float s = red[t] + red[t + 64];
        for (int o = 32; o; o >>= 1) s += __shfl_xor(s, o, 64);
        if (t == 0) wsf[gi * 1024 + 516] = s;
      }
    }
  }
}

// ---- mixer: one block = one batch element; 4 waves = (gi x h-half); 3 barriers ----
__global__ __launch_bounds__(256, 4)
void mixer(const float* __restrict__ agent_qs,
           const float* __restrict__ entities,
           const int* __restrict__ emask,
           const float* __restrict__ fc1_b,
           const float* __restrict__ qkv_b,
           const unsigned short* __restrict__ wbf,
           const float* __restrict__ wsf,
           float* __restrict__ out) {
  __shared__ __align__(16) ushort_t sX1[2][4096];  // per gi: [mt2][kc4][512] tiles
  __shared__ __align__(16) ushort_t sK[2][4096];   // per gi: rm 32x128
  __shared__ __align__(16) ushort_t sQ[2][1024];   // per gi: rm 8x128
  __shared__ float sVP[2][4][32];
  __shared__ float sPart[4];
  __shared__ float sCnt;

  const int t = threadIdx.x;
  const int lane = t & 63;
  const int w = t >> 6;             // 0..3
  const int gi = w >> 1, mtl = w & 1;
  const int g = gi ? 3 : 1;
  const int kg = lane >> 4, r = lane & 15;
  const int b = blockIdx.x;

  const short8* W1f = (const short8*)wbf;
  const short8* Wkvf = (const short8*)(wbf + 16384);
  const short8* Wqf = (const short8*)(wbf + 53248);

  // masks
  const int mlane = emask[b * 32 + (lane & 31)];
  const int cnt = __popcll(__ballot((lane < 8) && (mlane == 0)));
  if (t == 0) sCnt = (float)cnt;

  // ---- phase B: x1 = relu(E @ W1^T + b1); wave computes h-rows [mtl*64, mtl*64+64) ----
  {
    u32x4 ef[2][2];
#pragma unroll
    for (int mt = 0; mt < 2; ++mt)
#pragma unroll
      for (int kc = 0; kc < 2; ++kc) {
        const float4* ep =
            (const float4*)(entities + (size_t)b * 2048 + (mt * 16 + r) * 64 + kc * 32 + kg * 8);
        float4 u0 = ep[0], u1 = ep[1];
        u32x4 v;
        v.x = pk2(u0.x, u0.y); v.y = pk2(u0.z, u0.w);
        v.z = pk2(u1.x, u1.y); v.w = pk2(u1.z, u1.w);
        ef[mt][kc] = v;
      }
    f32x4 ax[4][2];
#pragma unroll
    for (int j = 0; j < 4; ++j)
#pragma unroll
      for (int mt = 0; mt < 2; ++mt) ax[j][mt] = {0.f, 0.f, 0.f, 0.f};
#pragma unroll
    for (int kc = 0; kc < 2; ++kc)
#pragma unroll
      for (int j = 0; j < 4; ++j) {
        int nt = mtl * 4 + j;
        short8 wf = W1f[(gi * 16 + nt * 2 + kc) * 64 + lane];
#pragma unroll
        for (int mt = 0; mt < 2; ++mt)
          ax[j][mt] = __builtin_amdgcn_mfma_f32_16x16x32_bf16(wf, asfrag(ef[mt][kc]), ax[j][mt], 0, 0, 0);
      }
#pragma unroll
    for (int j = 0; j < 4; ++j) {
      int hbase = (mtl * 4 + j) * 16 + kg * 4;
      float4 b4 = *(const float4*)&fc1_b[g * 128 + hbase];
#pragma unroll
      for (int mt = 0; mt < 2; ++mt) {
        float v0 = fmaxf(ax[j][mt][0] + b4.x, 0.f);
        float v1 = fmaxf(ax[j][mt][1] + b4.y, 0.f);
        float v2 = fmaxf(ax[j][mt][2] + b4.z, 0.f);
        float v3 = fmaxf(ax[j][mt][3] + b4.w, 0.f);
        uint2 pkv;
        pkv.x = pk2(v0, v1);
        pkv.y = pk2(v2, v3);
        *(uint2*)&sX1[gi][(mt * 4 + (hbase >> 5)) * 512 + tile_addr(r, hbase & 31)] = pkv;
      }
    }
  }
  __syncthreads();

  // ---- phase C: [K | vproj] + Q; wave computes K h-rows [mtl*64,+64), Q same ----
  {
    f32x4 ak[4][2], av[2];
#pragma unroll
    for (int j = 0; j < 4; ++j)
#pragma unroll
      for (int mt = 0; mt < 2; ++mt) ak[j][mt] = {0.f, 0.f, 0.f, 0.f};
    av[0] = {0.f, 0.f, 0.f, 0.f};
    av[1] = {0.f, 0.f, 0.f, 0.f};
#pragma unroll
    for (int kc = 0; kc < 4; ++kc) {
      short8 xf0 = *(const short8*)&sX1[gi][kc * 512 + tile_addr(r, kg * 8)];
      short8 xf1 = *(const short8*)&sX1[gi][(4 + kc) * 512 + tile_addr(r, kg * 8)];
#pragma unroll
      for (int j = 0; j < 4; ++j) {
        int nt = mtl * 4 + j;
        short8 wf = Wkvf[(gi * 36 + nt * 4 + kc) * 64 + lane];
        ak[j][0] = __builtin_amdgcn_mfma_f32_16x16x32_bf16(wf, xf0, ak[j][0], 0, 0, 0);
        ak[j][1] = __builtin_amdgcn_mfma_f32_16x16x32_bf16(wf, xf1, ak[j][1], 0, 0, 0);
      }
      if (mtl == 0) {
        short8 wf8 = Wkvf[(gi * 36 + 8 * 4 + kc) * 64 + lane];
        av[0] = __builtin_amdgcn_mfma_f32_16x16x32_bf16(wf8, xf0, av[0], 0, 0, 0);
        av[1] = __builtin_amdgcn_mfma_f32_16x16x32_bf16(wf8, xf1, av[1], 0, 0, 0);
      }
    }
#pragma unroll
    for (int j = 0; j < 4; ++j) {
      int hbase = (mtl * 4 + j) * 16 + kg * 4;
      float4 b4 = *(const float4*)&qkv_b[g * 384 + 128 + hbase];
#pragma unroll
      for (int mt = 0; mt < 2; ++mt) {
        uint2 pkv;
        pkv.x = pk2(ak[j][mt][0] + b4.x, ak[j][mt][1] + b4.y);
        pkv.y = pk2(ak[j][mt][2] + b4.z, ak[j][mt][3] + b4.w);
        *(uint2*)&sK[gi][rm_addr(mt * 16 + r, hbase)] = pkv;
      }
    }
    if (mtl == 0 && kg == 0) {
#pragma unroll
      for (int mt = 0; mt < 2; ++mt)
#pragma unroll
        for (int reg = 0; reg < 4; ++reg)
          sVP[gi][reg][mt * 16 + r] = av[mt][reg] + wsf[gi * 1024 + 512 + reg];
    }
    // Q
    f32x4 aq[4];
#pragma unroll
    for (int j = 0; j < 4; ++j) aq[j] = {0.f, 0.f, 0.f, 0.f};
#pragma unroll
    for (int kc = 0; kc < 4; ++kc) {
      short8 xf0 = *(const short8*)&sX1[gi][kc * 512 + tile_addr(r, kg * 8)];
#pragma unroll
      for (int j = 0; j < 4; ++j)
        aq[j] = __builtin_amdgcn_mfma_f32_16x16x32_bf16(
            Wqf[(gi * 32 + (mtl * 4 + j) * 4 + kc) * 64 + lane], xf0, aq[j], 0, 0, 0);
    }
#pragma unroll
    for (int j = 0; j < 4; ++j) {
      int hbase = (mtl * 4 + j) * 16 + kg * 4;
      float4 b4 = *(const float4*)&qkv_b[g * 384 + hbase];
      uint2 pkv;
      pkv.x = pk2(aq[j][0] + b4.x, aq[j][1] + b4.y);
      pkv.y = pk2(aq[j][2] + b4.z, aq[j][3] + b4.w);
      if (r < 8) *(uint2*)&sQ[gi][rm_addr(r, hbase)] = pkv;
    }
  }
  __syncthreads();

  // ---- phase D: attention; wave = (gid, head-pair hp) ----
  {
    const int gid = w >> 1, hp = w & 1;
    const bool me0 = __shfl(mlane, r) == 0;
    const bool me1 = __shfl(mlane, 16 + r) == 0;
    bool aa[4];
#pragma unroll
    for (int reg = 0; reg < 4; ++reg) aa[reg] = __shfl(mlane, (kg * 4 + reg) & 7) == 0;
    float c_acc = 0.f;
#pragma unroll
    for (int hi = 0; hi < 2; ++hi) {
      const int hh = hp * 2 + hi;
      short8 qa = *(const short8*)&sQ[gid][rm_addr(lane & 7, hh * 32 + kg * 8)];
      short8 kb0 = *(const short8*)&sK[gid][rm_addr(r, hh * 32 + kg * 8)];
      short8 kb1 = *(const short8*)&sK[gid][rm_addr(16 + r, hh * 32 + kg * 8)];
      f32x4 z = {0.f, 0.f, 0.f, 0.f};
      f32x4 d0 = __builtin_amdgcn_mfma_f32_16x16x32_bf16(qa, kb0, z, 0, 0, 0);
      f32x4 d1 = __builtin_amdgcn_mfma_f32_16x16x32_bf16(qa, kb1, z, 0, 0, 0);
      float s0w = 0.f, s1w = 0.f;
#pragma unroll
      for (int reg = 0; reg < 4; ++reg) {
        float lg0 = (me0 && aa[reg]) ? d0[reg] * SCALE : -1e30f;
        float lg1 = (me1 && aa[reg]) ? d1[reg] * SCALE : -1e30f;
        float m = fmaxf(lg0, lg1);
#pragma unroll
        for (int o = 8; o; o >>= 1) m = fmaxf(m, __shfl_xor(m, o, 16));
        float p0 = lg0 > -1e29f ? __expf(lg0 - m) : 0.f;
        float p1 = lg1 > -1e29f ? __expf(lg1 - m) : 0.f;
        float s = p0 + p1;
#pragma unroll
        for (int o = 8; o; o >>= 1) s += __shfl_xor(s, o, 16);
        float inv = s > 0.f ? 1.f / s : 0.f;
        s0w += p0 * inv;
        s1w += p1 * inv;
      }
      float vp0 = sVP[gid][hh][r];
      float vp1 = sVP[gid][hh][16 + r];
      c_acc = fmaf(vp0, s0w, fmaf(vp1, s1w, c_acc));
    }
#pragma unroll
    for (int o = 16; o; o >>= 1) c_acc += __shfl_xor(c_acc, o, 32);
    if (lane == 0) sPart[w] = c_acc;
  }
  __syncthreads();

  if (t == 0) {
    const float4* qs = (const float4*)(agent_qs + (size_t)b * 8);
    float4 a = qs[0], b4 = qs[1];
    float qsum = a.x + a.y + a.z + a.w + b4.x + b4.y + b4.z + b4.w;
    float s0 = sPart[0] + sPart[1] + wsf[516] * sCnt;
    float s1 = sPart[2] + sPart[3] + wsf[1024 + 516] * sCnt;
    out[b] = qsum + s0 * 0.125f + s1 * (1.f / 256.f);
  }
}

extern "C" void kernel_launch(void* const* d_in, const int* in_sizes, int n_in,
                              void* d_out, int out_size, void* d_ws, size_t ws_size,
                              hipStream_t stream) {
  const float* agent_qs = (const float*)d_in[0];
  const float* entities = (const float*)d_in[1];
  const int* emask = (const int*)d_in[2];
  const float* fc1_w = (const float*)d_in[3];
  const float* fc1_b = (const float*)d_in[4];
  const float* qkv_w = (const float*)d_in[5];
  const float* qkv_b = (const float*)d_in[6];
  const float* out_w = (const float*)d_in[7];
  const float* out_b = (const float*)d_in[8];
  const float* fc2_w = (const float*)d_in[9];
  const float* fc2_b = (const float*)d_in[10];
  float* out = (float*)d_out;
  unsigned short* wbf = (unsigned short*)d_ws;
  float* wsf = (float*)((char*)d_ws + 172032);

  prep<<<48, 256, 0, stream>>>(fc1_w, qkv_w, qkv_b, out_w, out_b, fc2_w, fc2_b, wbf, wsf);
  mixer<<<NBLK, 256, 0, stream>>>(agent_qs, entities, emask, fc1_b, qkv_b, wbf, wsf, out);
}